// Round 7
// baseline (348.540 us; speedup 1.0000x reference)
//
#include <hip/hip_runtime.h>
#include <cstdint>
#include <cstddef>

#define DIN 1280
#define DOUT 3840
#define NEXP 6
#define RANK 16
#define TOKENS 16384
#define KPAD 1408   // 1280 x + 16 shared + 96 routed + 16 zero pad
#define NLOW 128    // padded low-rank cols (112 valid)

typedef __bf16 bf16x8 __attribute__((ext_vector_type(8)));
typedef float f32x4 __attribute__((ext_vector_type(4)));
typedef unsigned short u16x8 __attribute__((ext_vector_type(8)));

#define SB() __builtin_amdgcn_sched_barrier(0)
#define BAR() __builtin_amdgcn_s_barrier()

__device__ __forceinline__ unsigned short f2bf(float f) {
    unsigned u = __builtin_bit_cast(unsigned, f);
    u += 0x7fff + ((u >> 16) & 1);   // RNE
    return (unsigned short)(u >> 16);
}

__device__ __forceinline__ void async_load16(void* lds, const void* g) {
    __builtin_amdgcn_global_load_lds(
        (const __attribute__((address_space(1))) unsigned int*)g,
        (__attribute__((address_space(3))) unsigned int*)lds, 16, 0, 0);
}

// Build WcatT [DOUT][KPAD] bf16: rows n, cols k. k<1280: base_w[k][n];
// 1280..1295: shared_w2[k-1280][n]; 1296..1391: routed_w2 flat[k-1296][n]; else 0.
__global__ void prep_w2t(const float* __restrict__ base_w,
                         const float* __restrict__ shared_w2,
                         const float* __restrict__ routed_w2,
                         unsigned short* __restrict__ WT) {
    __shared__ unsigned short tile[32][33];
    int k0 = blockIdx.x * 32, n0 = blockIdx.y * 32;
    int tx = threadIdx.x, ty = threadIdx.y;
#pragma unroll
    for (int j = 0; j < 4; j++) {
        int k = k0 + ty + j * 8;
        int n = n0 + tx;
        float v;
        if (k < DIN)            v = base_w[(size_t)k * DOUT + n];
        else if (k < DIN + 16)  v = shared_w2[(size_t)(k - DIN) * DOUT + n];
        else if (k < DIN + 112) v = routed_w2[(size_t)(k - DIN - 16) * DOUT + n];
        else                    v = 0.f;
        tile[ty + j * 8][tx] = f2bf(v);
    }
    __syncthreads();
#pragma unroll
    for (int j = 0; j < 4; j++) {
        int n = n0 + ty + j * 8;
        int k = k0 + tx;
        WT[(size_t)n * KPAD + k] = tile[tx][ty + j * 8];
    }
}

// Build W1catT [NLOW][DIN] bf16: row n<16: shared_w1[:,n]; 16..111: routed_w1[e][:,r]; else 0.
__global__ void prep_w1t(const float* __restrict__ shared_w1,
                         const float* __restrict__ routed_w1,
                         unsigned short* __restrict__ W1T) {
    __shared__ unsigned short tile[32][33];
    int k0 = blockIdx.x * 32, n0 = blockIdx.y * 32;
    int tx = threadIdx.x, ty = threadIdx.y;
#pragma unroll
    for (int j = 0; j < 4; j++) {
        int k = k0 + ty + j * 8;
        int n = n0 + tx;
        float v = 0.f;
        if (n < 16) v = shared_w1[k * RANK + n];
        else if (n < 112) {
            int jj = n - 16, e = jj >> 4, r = jj & 15;
            v = routed_w1[(size_t)e * DIN * RANK + k * RANK + r];
        }
        tile[ty + j * 8][tx] = f2bf(v);
    }
    __syncthreads();
#pragma unroll
    for (int j = 0; j < 4; j++) {
        int n = n0 + ty + j * 8;
        int k = k0 + tx;
        W1T[(size_t)n * DIN + k] = tile[tx][ty + j * 8];
    }
}

// Per 8-token block: convert x -> bf16 into A[:, 0:1280] (vectorized 8-wide),
// zero A[:, 1392:1408], fp32 router logits -> softmax -> top-3 -> cw[T,6].
__global__ __launch_bounds__(256) void router_kernel(
    const float* __restrict__ x,
    const float* __restrict__ router_w,
    const float* __restrict__ router_b,
    unsigned short* __restrict__ A,
    float* __restrict__ cw) {
    int tid = threadIdx.x;
    size_t t0 = (size_t)blockIdx.x * 8;
    const float* xblk = x + t0 * DIN;
    unsigned short* Ablk = A + t0 * KPAD;

    for (int i = tid; i < 8 * (DIN / 8); i += 256) {
        int t = i / (DIN / 8), c = (i - t * (DIN / 8)) * 8;
        const float* xs = xblk + (size_t)t * DIN + c;
        f32x4 v0 = *(const f32x4*)xs;
        f32x4 v1 = *(const f32x4*)(xs + 4);
        u16x8 o;
#pragma unroll
        for (int j = 0; j < 4; j++) { o[j] = f2bf(v0[j]); o[4 + j] = f2bf(v1[j]); }
        *(u16x8*)&Ablk[(size_t)t * KPAD + c] = o;
    }
    if (tid < 128) {
        int t = tid >> 4, c = tid & 15;
        Ablk[t * KPAD + DIN + 112 + c] = 0;
    }

    int tg = tid >> 5, lj = tid & 31;
    const float* xt = xblk + (size_t)tg * DIN;
    float acc[6] = {0.f, 0.f, 0.f, 0.f, 0.f, 0.f};
    for (int k = lj; k < DIN; k += 32) {
        float xv = xt[k];
        const float* wr = router_w + k * NEXP;
#pragma unroll
        for (int e = 0; e < NEXP; e++) acc[e] = fmaf(xv, wr[e], acc[e]);
    }
#pragma unroll
    for (int off = 16; off > 0; off >>= 1)
#pragma unroll
        for (int e = 0; e < NEXP; e++) acc[e] += __shfl_xor(acc[e], off);

    float mx = -1e30f;
#pragma unroll
    for (int e = 0; e < NEXP; e++) { acc[e] += router_b[e]; mx = fmaxf(mx, acc[e]); }
    float g[6]; float s = 0.f;
#pragma unroll
    for (int e = 0; e < NEXP; e++) { g[e] = __expf(acc[e] - mx); s += g[e]; }
    float inv = 1.f / s;
    if (lj < NEXP) {
        float ge = g[lj];
        int cnt = 0;
#pragma unroll
        for (int e = 0; e < NEXP; e++) {
            if (e == lj) continue;
            if (g[e] > ge || (g[e] == ge && e < lj)) cnt++;  // tie -> lowest index wins
        }
        cw[(t0 + tg) * NEXP + lj] = (cnt < 3) ? ge * inv : 0.f;
    }
}

// A[t, 1280+j] = bf16( (j<16 ? 1 : cw[t][(j-16)/16]) * (H0+H1)[t][j] ), j in [0,112)
__global__ __launch_bounds__(256) void combine_kernel(
    const float* __restrict__ H, const float* __restrict__ cw,
    unsigned short* __restrict__ A) {
    int i = blockIdx.x * 256 + threadIdx.x;  // < TOKENS*112
    int t = i / 112, j = i - t * 112;
    float h = H[(size_t)t * NLOW + j] + H[(size_t)TOKENS * NLOW + (size_t)t * NLOW + j];
    float f = (j < 16) ? 1.0f : cw[t * NEXP + ((j - 16) >> 4)];
    A[(size_t)t * KPAD + DIN + j] = f2bf(f * h);
}

// Small GEMM H[z][m,n] = A[m, z*640 : z*640+640] @ W1T[n, z*640 : ...]^T.
__global__ __launch_bounds__(256, 2) void gemm_small(
    const unsigned short* __restrict__ A,
    const unsigned short* __restrict__ BT,
    float* __restrict__ H) {
    __shared__ unsigned short ldsA[128 * 32];
    __shared__ unsigned short ldsB[128 * 32];
    const int KS = DIN / 2;  // 640
    int tid = threadIdx.x;
    int lane = tid & 63, wave = tid >> 6;
    int m0 = blockIdx.y * 128;
    int z = blockIdx.z;
    int wm = (wave >> 1) * 64, wn = (wave & 1) * 64;
    int lr = lane & 15, quad = lane >> 4;

    f32x4 acc[4][4] = {};
    const unsigned short* Abase = A + (size_t)m0 * KPAD + z * KS;
    const unsigned short* Bbase = BT + z * KS;
    float* Cbase = H + (size_t)z * TOKENS * NLOW;

    for (int k0 = 0; k0 < KS; k0 += 32) {
#pragma unroll
        for (int i = 0; i < 2; i++) {
            int c = i * 256 + tid;
            int row = c >> 2;
            int col = (c & 3) << 3;
            async_load16(&ldsA[(i * 256 + wave * 64) * 8],
                         Abase + (size_t)row * KPAD + k0 + col);
            async_load16(&ldsB[(i * 256 + wave * 64) * 8],
                         Bbase + (size_t)row * DIN + k0 + col);
        }
        __syncthreads();
        bf16x8 af[4], bf[4];
#pragma unroll
        for (int mi = 0; mi < 4; mi++)
            af[mi] = *(const bf16x8*)&ldsA[(wm + mi * 16 + lr) * 32 + quad * 8];
#pragma unroll
        for (int ni = 0; ni < 4; ni++)
            bf[ni] = *(const bf16x8*)&ldsB[(wn + ni * 16 + lr) * 32 + quad * 8];
#pragma unroll
        for (int mi = 0; mi < 4; mi++)
#pragma unroll
            for (int ni = 0; ni < 4; ni++)
                acc[mi][ni] = __builtin_amdgcn_mfma_f32_16x16x32_bf16(
                    af[mi], bf[ni], acc[mi][ni], 0, 0, 0);
        __syncthreads();
    }
#pragma unroll
    for (int ni = 0; ni < 4; ni++) {
        int gn = wn + ni * 16 + lr;
#pragma unroll
        for (int mi = 0; mi < 4; mi++) {
            int gm = m0 + wm + mi * 16 + quad * 4;
            f32x4 v = acc[mi][ni];
#pragma unroll
            for (int r = 0; r < 4; r++)
                Cbase[(size_t)(gm + r) * NLOW + gn] = v[r];
        }
    }
}

// ---------- big GEMM: 256x128 tile, BK=32, A direct global->reg, B via LDS ring-4 ----------
// R6 fact: occupancy 2x'd, MfmaUtil unchanged 34% -> the cap is the operand-delivery
// chain through LDS (barrier + lgkm drains), not TLP/BW/sync-count (M1: 84.5%).
// Here: A-frags are loaded straight from global into VGPRs (16 rows x 64B segments,
// L2/L3-served, A chip traffic ~1.4 GB), prefetched 1 tile ahead, waited via
// compiler-tracked vmcnt -- the lgkm/barrier chain is gone for A. B (small) stays
// LDS-staged: 8 KB/tile, ring-4, staged 2 tiles ahead, certified by counted vmcnt(6)
// (FIFO: Bst(t) is 7th-newest at its certify point; tails 5/2), 1 barrier/tile.
// Wave layout 8M x 1N: wave owns 32x128, acc[2][8]; A rows read by exactly 1 wave.

#define BM 256
#define BN 128
#define BKS 32
#define NKT (KPAD / BKS)   // 44

__global__ __launch_bounds__(512, 2) void gemm256(
    const unsigned short* __restrict__ A,
    const unsigned short* __restrict__ BT,
    const float* __restrict__ bias,
    float* __restrict__ C) {
    __shared__ unsigned short lB[4][BN * BKS];   // 4 x 8 KB ring

    int tid = threadIdx.x;
    int lane = tid & 63, wave = tid >> 6;
    int bid = blockIdx.x;
    // XCD swizzle (1920 % 8 == 0, bijective): XCD x owns m-tiles [8x, 8x+8).
    int xcd = bid & 7, lid = bid >> 3;
    int mt = xcd * 8 + (lid & 7);   // 0..63
    int nt = lid >> 3;              // 0..29
    int m0 = mt * BM, n0 = nt * BN;

    int lr = lane & 15, quad = lane >> 4;

    // B staging (R6-verified involution): thread writes LDS chunk (tid&3) of row
    // (tid>>2) linearly; source takes chunk (tid&3)^((tid>>3)&3); reads apply
    // quad^((row>>1)&3).  8 KB = 1 gload_lds per thread per tile.
    int srow = tid >> 2;
    int scg = (tid & 3) ^ ((tid >> 3) & 3);
    const unsigned short* bSrc = BT + (size_t)(n0 + srow) * KPAD + scg * 8;

    // A direct: this wave owns rows [wave*32, wave*32+32); lane reads 16B at
    // row (wave*32 + mi*16 + lr), cols [t*32 + quad*8, +8).
    const unsigned short* aRow = A + (size_t)(m0 + wave * 32 + lr) * KPAD + quad * 8;

    f32x4 acc[2][8] = {};
    bf16x8 af[2][2];   // [slot = tile&1][mi]

    auto stB = [&](int t) {
        async_load16(&lB[t & 3][0] + (size_t)tid * 8, bSrc + (size_t)t * BKS);
    };

    // Prologue: Bst(0), Bst(1), A(0) -> slot 0.
    stB(0);
    stB(1);
    af[0][0] = *(const bf16x8*)aRow;
    af[0][1] = *(const bf16x8*)(aRow + (size_t)16 * KPAD);
    SB();

#pragma unroll 2
    for (int t = 0; t < NKT - 2; ++t) {   // steady: t = 0..41 (guards always true)
        // s1: issue A(t+1) -> slot (t+1)&1 (holds A(t-1), consumed last iter);
        //     issue Bst(t+2) -> ring buf (t+2)&3 (last read tile t-2; separated
        //     from that read by barrier(t-1)).
        const unsigned short* aT = aRow + (size_t)(t + 1) * BKS;
        af[(t + 1) & 1][0] = *(const bf16x8*)aT;
        af[(t + 1) & 1][1] = *(const bf16x8*)(aT + (size_t)16 * KPAD);
        stB(t + 2);
        SB();
        // s2: certify Bst(t).  Queue (oldest->newest) after it: [A(t)x2? no --
        // steady: Bst(t) issued at iter t-2; after it: iters t-1,t = 2x(2A+1B) = 6.
        asm volatile("s_waitcnt vmcnt(6)" ::: "memory");
        SB(); BAR(); SB();   // s3: B(t) readable by all waves
        // s4: B frags + MFMA (compiler emits counted lgkm for bf, vm for af).
        const unsigned short* b_cur = &lB[t & 3][0];
        bf16x8 bf[8];
#pragma unroll
        for (int ni = 0; ni < 8; ni++) {
            int row = ni * 16 + lr;
            int off = row * 64 + ((quad ^ ((row >> 1) & 3)) << 4);
            bf[ni] = *(const bf16x8*)((const char*)b_cur + off);
        }
        __builtin_amdgcn_s_setprio(1);
#pragma unroll
        for (int mi = 0; mi < 2; mi++)
#pragma unroll
            for (int ni = 0; ni < 8; ni++)
                acc[mi][ni] = __builtin_amdgcn_mfma_f32_16x16x32_bf16(
                    af[t & 1][mi], bf[ni], acc[mi][ni], 0, 0, 0);
        __builtin_amdgcn_s_setprio(0);
        SB();
    }

    // Tail t = 42: issue A(43); no Bst.  After Bst(42) (issued iter 40, last):
    // iter41 [A42x2, Bst43] + here [A43x2] = 5 -> vmcnt(5).
    {
        const unsigned short* aT = aRow + (size_t)43 * BKS;
        af[1][0] = *(const bf16x8*)aT;
        af[1][1] = *(const bf16x8*)(aT + (size_t)16 * KPAD);
        SB();
        asm volatile("s_waitcnt vmcnt(5)" ::: "memory");
        SB(); BAR(); SB();
        const unsigned short* b_cur = &lB[42 & 3][0];
        bf16x8 bf[8];
#pragma unroll
        for (int ni = 0; ni < 8; ni++) {
            int row = ni * 16 + lr;
            int off = row * 64 + ((quad ^ ((row >> 1) & 3)) << 4);
            bf[ni] = *(const bf16x8*)((const char*)b_cur + off);
        }
        __builtin_amdgcn_s_setprio(1);
#pragma unroll
        for (int mi = 0; mi < 2; mi++)
#pragma unroll
            for (int ni = 0; ni < 8; ni++)
                acc[mi][ni] = __builtin_amdgcn_mfma_f32_16x16x32_bf16(
                    af[0][mi], bf[ni], acc[mi][ni], 0, 0, 0);
        __builtin_amdgcn_s_setprio(0);
        SB();
    }
    // Tail t = 43.  After Bst(43) (issued iter 41, last): [A43x2] = 2 -> vmcnt(2).
    {
        asm volatile("s_waitcnt vmcnt(2)" ::: "memory");
        SB(); BAR(); SB();
        const unsigned short* b_cur = &lB[43 & 3][0];
        bf16x8 bf[8];
#pragma unroll
        for (int ni = 0; ni < 8; ni++) {
            int row = ni * 16 + lr;
            int off = row * 64 + ((quad ^ ((row >> 1) & 3)) << 4);
            bf[ni] = *(const bf16x8*)((const char*)b_cur + off);
        }
        __builtin_amdgcn_s_setprio(1);
#pragma unroll
        for (int mi = 0; mi < 2; mi++)
#pragma unroll
            for (int ni = 0; ni < 8; ni++)
                acc[mi][ni] = __builtin_amdgcn_mfma_f32_16x16x32_bf16(
                    af[1][mi], bf[ni], acc[mi][ni], 0, 0, 0);
        __builtin_amdgcn_s_setprio(0);
        SB();
    }

    // Epilogue: C/D layout col = lane&15, row = quad*4 + reg (verified mapping)
#pragma unroll
    for (int mi = 0; mi < 2; mi++) {
        int gm = m0 + wave * 32 + mi * 16 + quad * 4;
#pragma unroll
        for (int ni = 0; ni < 8; ni++) {
            int gn = n0 + ni * 16 + lr;
            float bv = bias[gn];
            f32x4 v = acc[mi][ni];
#pragma unroll
            for (int r = 0; r < 4; r++)
                C[(size_t)(gm + r) * DOUT + gn] = v[r] + bv;
        }
    }
}

extern "C" void kernel_launch(void* const* d_in, const int* in_sizes, int n_in,
                              void* d_out, int out_size, void* d_ws, size_t ws_size,
                              hipStream_t stream) {
    const float* x         = (const float*)d_in[0];
    const float* base_w    = (const float*)d_in[1];
    const float* base_b    = (const float*)d_in[2];
    const float* shared_w1 = (const float*)d_in[3];
    const float* shared_w2 = (const float*)d_in[4];
    const float* routed_w1 = (const float*)d_in[5];
    const float* routed_w2 = (const float*)d_in[6];
    const float* router_w  = (const float*)d_in[7];
    const float* router_b  = (const float*)d_in[8];
    float* out = (float*)d_out;

    char* ws = (char*)d_ws;
    size_t off = 0;
    unsigned short* A     = (unsigned short*)(ws + off); off += (size_t)TOKENS * KPAD * 2;
    unsigned short* WcatT = (unsigned short*)(ws + off); off += (size_t)DOUT * KPAD * 2;
    unsigned short* W1T   = (unsigned short*)(ws + off); off += (size_t)NLOW * DIN * 2;
    float* H              = (float*)(ws + off);          off += (size_t)2 * TOKENS * NLOW * 4;
    float* cw             = (float*)(ws + off);          off += (size_t)TOKENS * NEXP * 4;

    prep_w2t<<<dim3(KPAD / 32, DOUT / 32), dim3(32, 8), 0, stream>>>(
        base_w, shared_w2, routed_w2, WcatT);
    prep_w1t<<<dim3(DIN / 32, NLOW / 32), dim3(32, 8), 0, stream>>>(
        shared_w1, routed_w1, W1T);
    router_kernel<<<TOKENS / 8, 256, 0, stream>>>(x, router_w, router_b, A, cw);
    gemm_small<<<dim3(1, TOKENS / 128, 2), 256, 0, stream>>>(A, W1T, H);
    combine_kernel<<<(TOKENS * 112) / 256, 256, 0, stream>>>(H, cw, A);
    gemm256<<<(TOKENS / BM) * (DOUT / BN), 512, 0, stream>>>(
        A, WcatT, base_b, out);
}

// Round 8
// 305.311 us; speedup vs baseline: 1.1416x; 1.1416x over previous
//
#include <hip/hip_runtime.h>
#include <cstdint>
#include <cstddef>

#define DIN 1280
#define DOUT 3840
#define NEXP 6
#define RANK 16
#define TOKENS 16384
#define KPAD 1408   // 1280 x + 16 shared + 96 routed + 16 zero pad
#define NLOW 128    // padded low-rank cols (112 valid)

typedef __bf16 bf16x8 __attribute__((ext_vector_type(8)));
typedef float f32x4 __attribute__((ext_vector_type(4)));
typedef unsigned short u16x8 __attribute__((ext_vector_type(8)));

#define SB() __builtin_amdgcn_sched_barrier(0)
#define BAR() __builtin_amdgcn_s_barrier()

__device__ __forceinline__ unsigned short f2bf(float f) {
    unsigned u = __builtin_bit_cast(unsigned, f);
    u += 0x7fff + ((u >> 16) & 1);   // RNE
    return (unsigned short)(u >> 16);
}

__device__ __forceinline__ void async_load16(void* lds, const void* g) {
    __builtin_amdgcn_global_load_lds(
        (const __attribute__((address_space(1))) unsigned int*)g,
        (__attribute__((address_space(3))) unsigned int*)lds, 16, 0, 0);
}

// Build WcatT [DOUT][KPAD] bf16: rows n, cols k. k<1280: base_w[k][n];
// 1280..1295: shared_w2[k-1280][n]; 1296..1391: routed_w2 flat[k-1296][n]; else 0.
__global__ void prep_w2t(const float* __restrict__ base_w,
                         const float* __restrict__ shared_w2,
                         const float* __restrict__ routed_w2,
                         unsigned short* __restrict__ WT) {
    __shared__ unsigned short tile[32][33];
    int k0 = blockIdx.x * 32, n0 = blockIdx.y * 32;
    int tx = threadIdx.x, ty = threadIdx.y;
#pragma unroll
    for (int j = 0; j < 4; j++) {
        int k = k0 + ty + j * 8;
        int n = n0 + tx;
        float v;
        if (k < DIN)            v = base_w[(size_t)k * DOUT + n];
        else if (k < DIN + 16)  v = shared_w2[(size_t)(k - DIN) * DOUT + n];
        else if (k < DIN + 112) v = routed_w2[(size_t)(k - DIN - 16) * DOUT + n];
        else                    v = 0.f;
        tile[ty + j * 8][tx] = f2bf(v);
    }
    __syncthreads();
#pragma unroll
    for (int j = 0; j < 4; j++) {
        int n = n0 + ty + j * 8;
        int k = k0 + tx;
        WT[(size_t)n * KPAD + k] = tile[tx][ty + j * 8];
    }
}

// Build W1catT [NLOW][DIN] bf16: row n<16: shared_w1[:,n]; 16..111: routed_w1[e][:,r]; else 0.
__global__ void prep_w1t(const float* __restrict__ shared_w1,
                         const float* __restrict__ routed_w1,
                         unsigned short* __restrict__ W1T) {
    __shared__ unsigned short tile[32][33];
    int k0 = blockIdx.x * 32, n0 = blockIdx.y * 32;
    int tx = threadIdx.x, ty = threadIdx.y;
#pragma unroll
    for (int j = 0; j < 4; j++) {
        int k = k0 + ty + j * 8;
        int n = n0 + tx;
        float v = 0.f;
        if (n < 16) v = shared_w1[k * RANK + n];
        else if (n < 112) {
            int jj = n - 16, e = jj >> 4, r = jj & 15;
            v = routed_w1[(size_t)e * DIN * RANK + k * RANK + r];
        }
        tile[ty + j * 8][tx] = f2bf(v);
    }
    __syncthreads();
#pragma unroll
    for (int j = 0; j < 4; j++) {
        int n = n0 + ty + j * 8;
        int k = k0 + tx;
        W1T[(size_t)n * DIN + k] = tile[tx][ty + j * 8];
    }
}

// Per 8-token block: convert x -> bf16 into A[:, 0:1280] (vectorized 8-wide),
// zero A[:, 1392:1408], fp32 router logits -> softmax -> top-3 -> cw[T,6].
__global__ __launch_bounds__(256) void router_kernel(
    const float* __restrict__ x,
    const float* __restrict__ router_w,
    const float* __restrict__ router_b,
    unsigned short* __restrict__ A,
    float* __restrict__ cw) {
    int tid = threadIdx.x;
    size_t t0 = (size_t)blockIdx.x * 8;
    const float* xblk = x + t0 * DIN;
    unsigned short* Ablk = A + t0 * KPAD;

    for (int i = tid; i < 8 * (DIN / 8); i += 256) {
        int t = i / (DIN / 8), c = (i - t * (DIN / 8)) * 8;
        const float* xs = xblk + (size_t)t * DIN + c;
        f32x4 v0 = *(const f32x4*)xs;
        f32x4 v1 = *(const f32x4*)(xs + 4);
        u16x8 o;
#pragma unroll
        for (int j = 0; j < 4; j++) { o[j] = f2bf(v0[j]); o[4 + j] = f2bf(v1[j]); }
        *(u16x8*)&Ablk[(size_t)t * KPAD + c] = o;
    }
    if (tid < 128) {
        int t = tid >> 4, c = tid & 15;
        Ablk[t * KPAD + DIN + 112 + c] = 0;
    }

    int tg = tid >> 5, lj = tid & 31;
    const float* xt = xblk + (size_t)tg * DIN;
    float acc[6] = {0.f, 0.f, 0.f, 0.f, 0.f, 0.f};
    for (int k = lj; k < DIN; k += 32) {
        float xv = xt[k];
        const float* wr = router_w + k * NEXP;
#pragma unroll
        for (int e = 0; e < NEXP; e++) acc[e] = fmaf(xv, wr[e], acc[e]);
    }
#pragma unroll
    for (int off = 16; off > 0; off >>= 1)
#pragma unroll
        for (int e = 0; e < NEXP; e++) acc[e] += __shfl_xor(acc[e], off);

    float mx = -1e30f;
#pragma unroll
    for (int e = 0; e < NEXP; e++) { acc[e] += router_b[e]; mx = fmaxf(mx, acc[e]); }
    float g[6]; float s = 0.f;
#pragma unroll
    for (int e = 0; e < NEXP; e++) { g[e] = __expf(acc[e] - mx); s += g[e]; }
    float inv = 1.f / s;
    if (lj < NEXP) {
        float ge = g[lj];
        int cnt = 0;
#pragma unroll
        for (int e = 0; e < NEXP; e++) {
            if (e == lj) continue;
            if (g[e] > ge || (g[e] == ge && e < lj)) cnt++;  // tie -> lowest index wins
        }
        cw[(t0 + tg) * NEXP + lj] = (cnt < 3) ? ge * inv : 0.f;
    }
}

// A[t, 1280+j] = bf16( (j<16 ? 1 : cw[t][(j-16)/16]) * (H0+H1)[t][j] ), j in [0,112)
__global__ __launch_bounds__(256) void combine_kernel(
    const float* __restrict__ H, const float* __restrict__ cw,
    unsigned short* __restrict__ A) {
    int i = blockIdx.x * 256 + threadIdx.x;  // < TOKENS*112
    int t = i / 112, j = i - t * 112;
    float h = H[(size_t)t * NLOW + j] + H[(size_t)TOKENS * NLOW + (size_t)t * NLOW + j];
    float f = (j < 16) ? 1.0f : cw[t * NEXP + ((j - 16) >> 4)];
    A[(size_t)t * KPAD + DIN + j] = f2bf(f * h);
}

// Small GEMM H[z][m,n] = A[m, z*640 : z*640+640] @ W1T[n, z*640 : ...]^T.
__global__ __launch_bounds__(256, 2) void gemm_small(
    const unsigned short* __restrict__ A,
    const unsigned short* __restrict__ BT,
    float* __restrict__ H) {
    __shared__ unsigned short ldsA[128 * 32];
    __shared__ unsigned short ldsB[128 * 32];
    const int KS = DIN / 2;  // 640
    int tid = threadIdx.x;
    int lane = tid & 63, wave = tid >> 6;
    int m0 = blockIdx.y * 128;
    int z = blockIdx.z;
    int wm = (wave >> 1) * 64, wn = (wave & 1) * 64;
    int lr = lane & 15, quad = lane >> 4;

    f32x4 acc[4][4] = {};
    const unsigned short* Abase = A + (size_t)m0 * KPAD + z * KS;
    const unsigned short* Bbase = BT + z * KS;
    float* Cbase = H + (size_t)z * TOKENS * NLOW;

    for (int k0 = 0; k0 < KS; k0 += 32) {
#pragma unroll
        for (int i = 0; i < 2; i++) {
            int c = i * 256 + tid;
            int row = c >> 2;
            int col = (c & 3) << 3;
            async_load16(&ldsA[(i * 256 + wave * 64) * 8],
                         Abase + (size_t)row * KPAD + k0 + col);
            async_load16(&ldsB[(i * 256 + wave * 64) * 8],
                         Bbase + (size_t)row * DIN + k0 + col);
        }
        __syncthreads();
        bf16x8 af[4], bf[4];
#pragma unroll
        for (int mi = 0; mi < 4; mi++)
            af[mi] = *(const bf16x8*)&ldsA[(wm + mi * 16 + lr) * 32 + quad * 8];
#pragma unroll
        for (int ni = 0; ni < 4; ni++)
            bf[ni] = *(const bf16x8*)&ldsB[(wn + ni * 16 + lr) * 32 + quad * 8];
#pragma unroll
        for (int mi = 0; mi < 4; mi++)
#pragma unroll
            for (int ni = 0; ni < 4; ni++)
                acc[mi][ni] = __builtin_amdgcn_mfma_f32_16x16x32_bf16(
                    af[mi], bf[ni], acc[mi][ni], 0, 0, 0);
        __syncthreads();
    }
#pragma unroll
    for (int ni = 0; ni < 4; ni++) {
        int gn = wn + ni * 16 + lr;
#pragma unroll
        for (int mi = 0; mi < 4; mi++) {
            int gm = m0 + wm + mi * 16 + quad * 4;
            f32x4 v = acc[mi][ni];
#pragma unroll
            for (int r = 0; r < 4; r++)
                Cbase[(size_t)(gm + r) * NLOW + gn] = v[r];
        }
    }
}

// ---------- big GEMM: literal m201 8-phase port. 256x256, BK=64, 8 waves ----------
// Every phase: {ds_reads for THIS phase's MFMA (12 at tile-start, else 4),
//   2 x global_load_lds (one half-tile), [lgkm8 if 12 reads], BAR, lgkm0+SB,
//   setprio(1), 16 MFMA, setprio(0), BAR}.  4 phases per K-tile; B-frags read in
// ph1, held in regs across the tile.  Staging: ph1/ph2 -> A(t+1) (buf c^1 A-region,
// free since end of tile t-1); ph3/ph4 -> B(t+2) (buf c B-region, free after ph1).
// vmcnt(4) once per tile at ph4 (FIFO: queue = [B(t+1)x4? no: A(t+1)x4? ->
// after A(t+1)pr1 only B(t+2)x4 newer => 4); prologue B0,A0,B1 -> vmcnt(4);
// tails vmcnt(0).  2 K-tiles per loop iteration so buffer indices are constants.

#define MFMA16(MB) do { \
    _Pragma("unroll") for (int ks_ = 0; ks_ < 2; ks_++) \
    _Pragma("unroll") for (int mq_ = 0; mq_ < 2; mq_++) \
    _Pragma("unroll") for (int ni_ = 0; ni_ < 4; ni_++) \
        acc[(MB) + mq_][ni_] = __builtin_amdgcn_mfma_f32_16x16x32_bf16( \
            aq[mq_][ks_], bfr[ni_][ks_], acc[(MB) + mq_][ni_], 0, 0, 0); \
} while (0)

// One K-tile body, buffer index CBUF is a compile-time constant.
#define TILE_BODY(CBUF) do { \
    const int t_ = 2 * tt + (CBUF); \
    const int k0_ = t_ * 64; \
    const unsigned short* a_cur = &lA[CBUF][0]; \
    const unsigned short* b_cur = &lB[CBUF][0]; \
    unsigned short* aN = &lA[(CBUF) ^ 1][0]; \
    unsigned short* bC = &lB[CBUF][0]; \
    const bool stA_ok = (t_ + 1 < NKT22); \
    const bool stB_ok = (t_ + 2 < NKT22); \
    bf16x8 bfr[4][2]; \
    bf16x8 aq[2][2]; \
    /* ---- phase 1: 8 B-reads + 4 A-reads (mi 0,1), stage A(t+1) pr0 ---- */ \
    _Pragma("unroll") for (int ni_ = 0; ni_ < 4; ni_++) { \
        bfr[ni_][0] = rdB(b_cur, ni_, 0); bfr[ni_][1] = rdB(b_cur, ni_, 1); } \
    aq[0][0] = rdA(a_cur, 0, 0); aq[0][1] = rdA(a_cur, 0, 1); \
    aq[1][0] = rdA(a_cur, 1, 0); aq[1][1] = rdA(a_cur, 1, 1); \
    if (stA_ok) stA2(aN, k0_ + 64, 0); \
    SB(); \
    asm volatile("s_waitcnt lgkmcnt(8)" ::: "memory"); \
    SB(); BAR(); \
    asm volatile("s_waitcnt lgkmcnt(0)" ::: "memory"); SB(); \
    __builtin_amdgcn_s_setprio(1); MFMA16(0); __builtin_amdgcn_s_setprio(0); \
    SB(); BAR(); SB(); \
    /* ---- phase 2: 4 A-reads (mi 2,3), stage A(t+1) pr1 ---- */ \
    aq[0][0] = rdA(a_cur, 2, 0); aq[0][1] = rdA(a_cur, 2, 1); \
    aq[1][0] = rdA(a_cur, 3, 0); aq[1][1] = rdA(a_cur, 3, 1); \
    if (stA_ok) stA2(aN, k0_ + 64, 1); \
    SB(); BAR(); \
    asm volatile("s_waitcnt lgkmcnt(0)" ::: "memory"); SB(); \
    __builtin_amdgcn_s_setprio(1); MFMA16(2); __builtin_amdgcn_s_setprio(0); \
    SB(); BAR(); SB(); \
    /* ---- phase 3: 4 A-reads (mi 4,5), stage B(t+2) pr0 ---- */ \
    aq[0][0] = rdA(a_cur, 4, 0); aq[0][1] = rdA(a_cur, 4, 1); \
    aq[1][0] = rdA(a_cur, 5, 0); aq[1][1] = rdA(a_cur, 5, 1); \
    if (stB_ok) stB2(bC, k0_ + 128, 0); \
    SB(); BAR(); \
    asm volatile("s_waitcnt lgkmcnt(0)" ::: "memory"); SB(); \
    __builtin_amdgcn_s_setprio(1); MFMA16(4); __builtin_amdgcn_s_setprio(0); \
    SB(); BAR(); SB(); \
    /* ---- phase 4: 4 A-reads (mi 6,7), stage B(t+2) pr1, tile-end vmcnt ---- */ \
    aq[0][0] = rdA(a_cur, 6, 0); aq[0][1] = rdA(a_cur, 6, 1); \
    aq[1][0] = rdA(a_cur, 7, 0); aq[1][1] = rdA(a_cur, 7, 1); \
    if (stB_ok) stB2(bC, k0_ + 128, 1); \
    SB(); BAR(); \
    asm volatile("s_waitcnt lgkmcnt(0)" ::: "memory"); SB(); \
    __builtin_amdgcn_s_setprio(1); MFMA16(6); __builtin_amdgcn_s_setprio(0); \
    SB(); \
    if (stB_ok)      asm volatile("s_waitcnt vmcnt(4)" ::: "memory"); \
    else if (stA_ok) asm volatile("s_waitcnt vmcnt(0)" ::: "memory"); \
    SB(); BAR(); SB(); \
} while (0)

#define NKT22 22

__global__ __launch_bounds__(512, 2) void gemm256(
    const unsigned short* __restrict__ A,
    const unsigned short* __restrict__ BT,
    const float* __restrict__ bias,
    float* __restrict__ C) {
    __shared__ unsigned short lA[2][256 * 64];   // 64 KB
    __shared__ unsigned short lB[2][256 * 64];   // 64 KB  (128 KB, 1 block/CU)

    int tid = threadIdx.x;
    int lane = tid & 63, wave = tid >> 6;
    int bid = blockIdx.x;
    // XCD swizzle (960 % 8 == 0, bijective): XCD x owns m-tiles [8x, 8x+8).
    int xcd = bid & 7, lid = bid >> 3;
    int mt = xcd * 8 + (lid & 7);   // 0..63
    int nt = lid >> 3;              // 0..14
    int m0 = mt * 256, n0 = nt * 256;

    int wm = (wave >> 2) * 128, wn = (wave & 3) * 64;   // 2M x 4N waves, 128x64 each
    int lr = lane & 15, quad = lane >> 4;
    int swz = (lr & 7) << 4;

    // Staging: lane l writes LDS chunk l%8 of row l/8; global source pre-swizzled
    // (chunk (l%8)^(l/8)) so LDS stays linear (m104/m173).
    int sr = lane >> 3;
    int sc = (lane & 7) ^ sr;
    const unsigned short* aSrc = A + (size_t)(m0 + wave * 32 + sr) * KPAD + sc * 8;
    const unsigned short* bSrc = BT + (size_t)(n0 + wave * 32 + sr) * KPAD + sc * 8;

    // Stage pair pr in {0,1}: rows [wave*32 + pr*16, +16); 2 gload_lds per call.
    auto stA2 = [&](unsigned short* dst, int k0, int pr) {
#pragma unroll
        for (int i = pr * 2; i < pr * 2 + 2; i++)
            async_load16(dst + (size_t)(wave * 32 + i * 8) * 64,
                         aSrc + (size_t)(i * 8) * KPAD + k0);
    };
    auto stB2 = [&](unsigned short* dst, int k0, int pr) {
#pragma unroll
        for (int i = pr * 2; i < pr * 2 + 2; i++)
            async_load16(dst + (size_t)(wave * 32 + i * 8) * 64,
                         bSrc + (size_t)(i * 8) * KPAD + k0);
    };
    // Fragment read, swizzle-aware (row&7 == lr&7 for all frags -> lane-constant XOR).
    auto rdA = [&](const unsigned short* base, int mi, int ks) -> bf16x8 {
        int row = wm + mi * 16 + lr;
        int off = row * 128 + (((ks << 6) | (quad << 4)) ^ swz);
        return *(const bf16x8*)((const char*)base + off);
    };
    auto rdB = [&](const unsigned short* base, int ni, int ks) -> bf16x8 {
        int row = wn + ni * 16 + lr;
        int off = row * 128 + (((ks << 6) | (quad << 4)) ^ swz);
        return *(const bf16x8*)((const char*)base + off);
    };

    f32x4 acc[8][4] = {};

    // Prologue (FIFO order matches steady state): B(0), A(0), B(1); vmcnt(4)
    // leaves B(1) in flight; barrier.
    stB2(&lB[0][0], 0, 0);  stB2(&lB[0][0], 0, 1);
    stA2(&lA[0][0], 0, 0);  stA2(&lA[0][0], 0, 1);
    stB2(&lB[1][0], 64, 0); stB2(&lB[1][0], 64, 1);
    asm volatile("s_waitcnt vmcnt(4)" ::: "memory");
    SB(); BAR(); SB();

#pragma unroll 1
    for (int tt = 0; tt < NKT22 / 2; ++tt) {
        TILE_BODY(0);
        TILE_BODY(1);
    }

    // Epilogue: C/D layout col = lane&15, row = quad*4 + reg (verified mapping)
#pragma unroll
    for (int mi = 0; mi < 8; mi++) {
        int gm = m0 + wm + mi * 16 + quad * 4;
#pragma unroll
        for (int ni = 0; ni < 4; ni++) {
            int gn = n0 + wn + ni * 16 + lr;
            float bv = bias[gn];
            f32x4 v = acc[mi][ni];
#pragma unroll
            for (int r = 0; r < 4; r++)
                C[(size_t)(gm + r) * DOUT + gn] = v[r] + bv;
        }
    }
}

extern "C" void kernel_launch(void* const* d_in, const int* in_sizes, int n_in,
                              void* d_out, int out_size, void* d_ws, size_t ws_size,
                              hipStream_t stream) {
    const float* x         = (const float*)d_in[0];
    const float* base_w    = (const float*)d_in[1];
    const float* base_b    = (const float*)d_in[2];
    const float* shared_w1 = (const float*)d_in[3];
    const float* shared_w2 = (const float*)d_in[4];
    const float* routed_w1 = (const float*)d_in[5];
    const float* routed_w2 = (const float*)d_in[6];
    const float* router_w  = (const float*)d_in[7];
    const float* router_b  = (const float*)d_in[8];
    float* out = (float*)d_out;

    char* ws = (char*)d_ws;
    size_t off = 0;
    unsigned short* A     = (unsigned short*)(ws + off); off += (size_t)TOKENS * KPAD * 2;
    unsigned short* WcatT = (unsigned short*)(ws + off); off += (size_t)DOUT * KPAD * 2;
    unsigned short* W1T   = (unsigned short*)(ws + off); off += (size_t)NLOW * DIN * 2;
    float* H              = (float*)(ws + off);          off += (size_t)2 * TOKENS * NLOW * 4;
    float* cw             = (float*)(ws + off);          off += (size_t)TOKENS * NEXP * 4;

    prep_w2t<<<dim3(KPAD / 32, DOUT / 32), dim3(32, 8), 0, stream>>>(
        base_w, shared_w2, routed_w2, WcatT);
    prep_w1t<<<dim3(DIN / 32, NLOW / 32), dim3(32, 8), 0, stream>>>(
        shared_w1, routed_w1, W1T);
    router_kernel<<<TOKENS / 8, 256, 0, stream>>>(x, router_w, router_b, A, cw);
    gemm_small<<<dim3(1, TOKENS / 128, 2), 256, 0, stream>>>(A, W1T, H);
    combine_kernel<<<(TOKENS * 112) / 256, 256, 0, stream>>>(H, cw, A);
    gemm256<<<(TOKENS / 256) * (DOUT / 256), 512, 0, stream>>>(
        A, WcatT, base_b, out);
}